// Round 18
// baseline (966.327 us; speedup 1.0000x reference)
//
#include <hip/hip_runtime.h>
#include <math.h>

// SRNN: S=16 steps, N=32768 nodes, E=131072 spatial edges.
// f16 MFMA gate GEMMs, B-resident weights. Numerics (kept, 14/14 stable):
//  - edge/node per-thread arithmetic = verified forms (absmax 3.90625e-3)
//  - CSR sorted ascending; agg as hi/lo f16 pair (K=192, MFMA order ks 0..5)
// Structure (r17, verified): edge_mega / batched gather (emb in-place into
// htAll) / node_mega (c in LDS, enc on-the-fly). THIS ROUND: edge h-flush at
// 4-B granularity (2 rows/wave -> 2-way banks = free; the uint2 form was a
// structural 4-way conflict: each 128B row spans all 32 banks, so 4 rows/wave
// always collide regardless of swizzle). Values bit-identical.

#define S_LEN 16
#define NN 32768
#define EE 131072

typedef _Float16 f16;
typedef _Float16 f16x8 __attribute__((ext_vector_type(8)));
typedef float f32x4 __attribute__((ext_vector_type(4)));

__device__ __forceinline__ float fsigmoid(float x) {
    return __builtin_amdgcn_rcpf(1.0f + __builtin_amdgcn_exp2f(-1.44269504f * x));
}
__device__ __forceinline__ float ftanh(float x) {
    const float e = __builtin_amdgcn_exp2f(2.88539008f * x);
    return 1.0f - 2.0f * __builtin_amdgcn_rcpf(e + 1.0f);
}

__device__ __forceinline__ unsigned int pk2(float a, float b) {
    union { f16 h[2]; unsigned int u; } x;
    x.h[0] = (f16)a; x.h[1] = (f16)b;
    return x.u;
}

__device__ __forceinline__ f16x8 ld_frag16(const void* p) {
    union { uint4 v; f16x8 f; } x;
    x.v = *(const uint4*)p;
    return x.f;
}

#define CSWZ(rl) (((((rl) >> 2) & 3) ^ ((rl) & 3)) << 4)

// ---------------- multi-step edge LSTM (temporal + spatial), H=64, TR=64 ----
__global__ __launch_bounds__(256) void edge_mega(
    const float* __restrict__ xT, const float* __restrict__ xS,
    const float* __restrict__ t_enc_w, const float* __restrict__ t_enc_b,
    const float* __restrict__ s_enc_w, const float* __restrict__ s_enc_b,
    const f16* __restrict__ WtT, const f16* __restrict__ WtS,
    const float* __restrict__ biasT, const float* __restrict__ biasS,
    f16* __restrict__ htAll, f16* __restrict__ hsAll,
    f16* __restrict__ htCarry,
    const float* __restrict__ cInT, const float* __restrict__ cInS,
    float* __restrict__ cOutT, float* __restrict__ cOutS,
    const int nsteps, const int writeC)
{
    constexpr int H = 64, K = 128, KSTEPS = 4, ROWB = 256, TR = 64;
    constexpr int RTN = TR / 16;
    __shared__ __align__(16) char Xls[TR * ROWB];
    __shared__ __align__(16) float cls[TR * H];
    __shared__ __align__(16) f16 hnx[TR * H];

    const int bT = NN / TR;
    const bool isT = (int)blockIdx.x < bT;
    const int row0 = (isT ? blockIdx.x : blockIdx.x - bT) * TR;
    const float* xbase = isT ? xT : xS;
    const size_t xstep = (size_t)(isT ? NN : EE) * 2;
    const float* enc_w = isT ? t_enc_w : s_enc_w;
    const float* enc_b = isT ? t_enc_b : s_enc_b;
    const f16*   Wt    = isT ? WtT : WtS;
    const float* bias  = isT ? biasT : biasS;
    f16* hAll = isT ? htAll : hsAll;
    const size_t hstep = (size_t)(isT ? NN : EE) * 64;
    const float* cIn  = (isT ? cInT : cInS) + (size_t)row0 * H;
    float*       cOut = (isT ? cOutT : cOutS) + (size_t)row0 * H;

    const int t = threadIdx.x;
    const int wv = t >> 6, l = t & 63;
    const int lane15 = l & 15, kgrp = l >> 4;
    const int col = wv * 16 + lane15;

    f16x8 bfrag[4][KSTEPS];
    #pragma unroll
    for (int q = 0; q < 4; ++q) {
        const int colq = q * H + col;
        const f16* bp = Wt + (size_t)colq * K + kgrp * 8;
        #pragma unroll
        for (int ks = 0; ks < KSTEPS; ++ks)
            bfrag[q][ks] = ld_frag16(bp + ks * 32);
    }

    for (int i = t; i < TR * H; i += 256) {
        const int r = i >> 6, j = i & 63;
        cls[(r << 6) + (j ^ CSWZ(r))] = cIn[i];
    }
    {
        const f16* hInit = isT ? (htCarry + (size_t)row0 * H)
                               : (hAll + (size_t)(nsteps - 1) * hstep + (size_t)row0 * H);
        for (int i = t; i < TR * (H / 4); i += 256) {
            const int r = i / (H / 4), j4 = (i % (H / 4)) * 4;
            const uint2 v = *(const uint2*)&hInit[(size_t)r * H + j4];
            const int byte = r * ROWB + ((H * 2 + j4 * 2) ^ ((r & 7) << 4));
            *(uint2*)(Xls + byte) = v;
        }
    }

    const float bi = bias[0 * H + col];
    const float bf = bias[1 * H + col];
    const float bg = bias[2 * H + col];
    const float bo = bias[3 * H + col];

    float xr0[8], xr1[8];
    {
        const float* xf = xbase;
        #pragma unroll
        for (int k2 = 0; k2 < 8; ++k2) {
            const int r = (t + k2 * 256) >> 5;
            xr0[k2] = xf[(size_t)(row0 + r) * 2 + 0];
            xr1[k2] = xf[(size_t)(row0 + r) * 2 + 1];
        }
    }

    for (int s = 0; s < nsteps; ++s) {
        #pragma unroll
        for (int k2 = 0; k2 < 8; ++k2) {
            const int i = t + k2 * 256;
            const int r = i >> 5, j2 = (i & 31) * 2;
            const float x0 = xr0[k2];
            const float x1 = xr1[k2];
            const float e0 = fmaxf(0.f, fmaf(x0, enc_w[j2],     fmaf(x1, enc_w[H + j2],     enc_b[j2])));
            const float e1 = fmaxf(0.f, fmaf(x0, enc_w[j2 + 1], fmaf(x1, enc_w[H + j2 + 1], enc_b[j2 + 1])));
            const int byte = r * ROWB + ((j2 * 2) ^ ((r & 7) << 4));
            *(unsigned int*)(Xls + byte) = pk2(e0, e1);
        }
        __syncthreads();

        if (s + 1 < nsteps) {
            const float* xf = xbase + (size_t)(s + 1) * xstep;
            #pragma unroll
            for (int k2 = 0; k2 < 8; ++k2) {
                const int r = (t + k2 * 256) >> 5;
                xr0[k2] = xf[(size_t)(row0 + r) * 2 + 0];
                xr1[k2] = xf[(size_t)(row0 + r) * 2 + 1];
            }
        }

        #pragma unroll
        for (int rt = 0; rt < RTN; ++rt) {
            const int arow = rt * 16 + lane15;
            const char* abase = Xls + arow * ROWB;
            f16x8 afrag[KSTEPS];
            #pragma unroll
            for (int ks = 0; ks < KSTEPS; ++ks) {
                const int byte = (ks * 64 + kgrp * 16) ^ ((arow & 7) << 4);
                afrag[ks] = ld_frag16(abase + byte);
            }
            f32x4 acc[4];
            #pragma unroll
            for (int q = 0; q < 4; ++q)
                #pragma unroll
                for (int r = 0; r < 4; ++r) acc[q][r] = 0.f;
            #pragma unroll
            for (int ks = 0; ks < KSTEPS; ++ks)
                #pragma unroll
                for (int q = 0; q < 4; ++q)
                    acc[q] = __builtin_amdgcn_mfma_f32_16x16x32_f16(
                        afrag[ks], bfrag[q][ks], acc[q], 0, 0, 0);
            #pragma unroll
            for (int reg = 0; reg < 4; ++reg) {
                const int rl = rt * 16 + kgrp * 4 + reg;
                const int sc = (rl << 6) + (col ^ CSWZ(rl));
                const float ig = fsigmoid(acc[0][reg] + bi);
                const float fg = fsigmoid(acc[1][reg] + bf);
                const float gg = ftanh(acc[2][reg] + bg);
                const float og = fsigmoid(acc[3][reg] + bo);
                const float c2 = fmaf(fg, cls[sc], ig * gg);
                cls[sc] = c2;
                hnx[sc] = (f16)(og * ftanh(c2));
            }
        }
        __syncthreads();

        // flush h at 4-B granularity: 2 rows/wave -> 2-way banks (free).
        // Same bytes as the former uint2 form; values bit-identical.
        f16* hOut = hAll + (size_t)s * hstep + (size_t)row0 * H;
        const bool carry = isT && (s == nsteps - 1);
        for (int i = t; i < TR * (H / 2); i += 256) {
            const int r = i >> 5, j2 = (i & 31) * 2;
            const unsigned int v = *(const unsigned int*)&hnx[(r << 6) + (j2 ^ CSWZ(r))];
            *(unsigned int*)&hOut[(size_t)r * H + j2] = v;
            if (carry) *(unsigned int*)&htCarry[(size_t)(row0 + r) * H + j2] = v;
            const int byte = r * ROWB + ((H * 2 + j2 * 2) ^ ((r & 7) << 4));
            *(unsigned int*)(Xls + byte) = v;
        }
    }

    if (writeC) {
        for (int i = t; i < TR * H; i += 256) {
            const int r = i >> 6, j = i & 63;
            cOut[i] = cls[(r << 6) + (j ^ CSWZ(r))];
        }
    }
}

// ---------------- batched gather + embed (all chunk steps, one dispatch) ----
// UNCHANGED from r17 (verified).
__global__ __launch_bounds__(256) void gather_embed_mega(
    const f16* __restrict__ htAll, const f16* __restrict__ hsAll,
    const int* __restrict__ ptr, const int* __restrict__ rowidx,
    const f16* __restrict__ Wt_ee2,  // [64][192]
    const float* __restrict__ ee_b)
{
    constexpr int TR = 64, K = 192, KSTEPS = 6, ROWB = 256;
    __shared__ __align__(16) char Xls[TR * ROWB];
    const int k2    = blockIdx.x >> 9;
    const int panel = blockIdx.x & 511;
    const int row0 = panel * TR;
    f16* htSlot = (f16*)htAll + (size_t)k2 * NN * 64;
    const f16* hsSlot = hsAll + (size_t)k2 * EE * 64;

    const int t = threadIdx.x;
    const int wv = t >> 6, l = t & 63;
    const int lane15 = l & 15, kgrp = l >> 4;
    const int col = wv * 16 + lane15;

    f16x8 bfrag[KSTEPS];
    {
        const f16* bp = Wt_ee2 + (size_t)col * K + kgrp * 8;
        #pragma unroll
        for (int ks = 0; ks < KSTEPS; ++ks) bfrag[ks] = ld_frag16(bp + ks * 32);
    }

    f16x8 af0[4], af1[4];
    #pragma unroll
    for (int rt = 0; rt < 4; ++rt) {
        const int arow = rt * 16 + lane15;
        af0[rt] = ld_frag16(&htSlot[(size_t)(row0 + arow) * 64 + kgrp * 8]);
        af1[rt] = ld_frag16(&htSlot[(size_t)(row0 + arow) * 64 + 32 + kgrp * 8]);
    }

    {
        const int r = t >> 2, q = t & 3;
        const int n = row0 + r;
        const int beg = ptr[n], end = ptr[n + 1];
        const unsigned int* hs32 = (const unsigned int*)hsSlot;
        float acc[16];
        #pragma unroll
        for (int j = 0; j < 16; ++j) acc[j] = 0.f;
        for (int i = beg; i < end; ++i) {
            const int e = rowidx[i];
            const unsigned int* ep = hs32 + (size_t)e * 32 + q * 8;
            #pragma unroll
            for (int j = 0; j < 8; ++j) {
                union { unsigned int u; f16 h[2]; } v;
                v.u = ep[j];
                acc[2 * j]     += (float)v.h[0];
                acc[2 * j + 1] += (float)v.h[1];
            }
        }
        #pragma unroll
        for (int j = 0; j < 8; ++j) {
            const float a0 = acc[2 * j], a1 = acc[2 * j + 1];
            const f16 h0 = (f16)a0, h1 = (f16)a1;
            const f16 l0 = (f16)(a0 - (float)h0), l1 = (f16)(a1 - (float)h1);
            union { f16 h[2]; unsigned int u; } hi, lo;
            hi.h[0] = h0; hi.h[1] = h1;
            lo.h[0] = l0; lo.h[1] = l1;
            const int bhi = r * ROWB + ((q * 32 + j * 4) ^ ((r & 7) << 4));
            const int blo = r * ROWB + ((128 + q * 32 + j * 4) ^ ((r & 7) << 4));
            *(unsigned int*)(Xls + bhi) = hi.u;
            *(unsigned int*)(Xls + blo) = lo.u;
        }
    }
    __syncthreads();

    const float bb = ee_b[col];
    #pragma unroll
    for (int rt = 0; rt < TR / 16; ++rt) {
        const int arow = rt * 16 + lane15;
        const char* abase = Xls + arow * ROWB;
        f16x8 afrag[KSTEPS];
        afrag[0] = af0[rt];
        afrag[1] = af1[rt];
        #pragma unroll
        for (int ks = 2; ks < KSTEPS; ++ks) {
            const int byte = (((ks - 2) * 64) + kgrp * 16) ^ ((arow & 7) << 4);
            afrag[ks] = ld_frag16(abase + byte);
        }
        f32x4 acc;
        #pragma unroll
        for (int r = 0; r < 4; ++r) acc[r] = 0.f;
        #pragma unroll
        for (int ks = 0; ks < KSTEPS; ++ks)
            acc = __builtin_amdgcn_mfma_f32_16x16x32_f16(afrag[ks], bfrag[ks], acc, 0, 0, 0);
        #pragma unroll
        for (int reg = 0; reg < 4; ++reg) {
            const int grow = row0 + rt * 16 + kgrp * 4 + reg;
            htSlot[(size_t)grow * 64 + col] = (f16)fmaxf(0.f, acc[reg] + bb);
        }
    }
}

// ---------------- multi-step node LSTM + fused output projection ------------
// UNCHANGED from r17 (verified).
__global__ __launch_bounds__(512) void node_mega(
    const float* __restrict__ xnBase,
    const f16* __restrict__ embAll,
    const f16* __restrict__ Wt,
    const float* __restrict__ bias,
    const float* __restrict__ n_enc_w, const float* __restrict__ n_enc_b,
    const float* __restrict__ out_w, const float* __restrict__ out_b,
    f16* __restrict__ hIO,
    float* __restrict__ c,
    float* __restrict__ outp,
    const int nsteps)
{
    constexpr int H = 128, K = 256, KSTEPS = 8, ROWB = 512, TR = 128;
    constexpr int RTN = TR / 16;
    __shared__ __align__(16) char Xls[TR * ROWB];
    __shared__ __align__(16) float clsN[TR * H];
    __shared__ float out_part[TR][8];

    const int row0 = blockIdx.x * TR;
    const int t = threadIdx.x;
    const int wv = t >> 6, l = t & 63;
    const int lane15 = l & 15, kgrp = l >> 4;
    const int col = wv * 16 + lane15;

    f16x8 bfrag[4][KSTEPS];
    #pragma unroll
    for (int q = 0; q < 4; ++q) {
        const int colq = q * H + col;
        const f16* bp = Wt + (size_t)colq * K + kgrp * 8;
        #pragma unroll
        for (int ks = 0; ks < KSTEPS; ++ks)
            bfrag[q][ks] = ld_frag16(bp + ks * 32);
    }

    for (int i = t; i < TR * (H / 4); i += 512) {
        const int r = i >> 5, j4 = (i & 31) * 4;
        const uint2 v = *(const uint2*)&hIO[(size_t)(row0 + r) * H + j4];
        const int byte = r * ROWB + ((H * 2 + j4 * 2) ^ ((r & 7) << 4));
        *(uint2*)(Xls + byte) = v;
        const float4 cv = *(const float4*)&c[(size_t)(row0 + r) * H + j4];
        *(float4*)&clsN[r * H + (j4 ^ CSWZ(r))] = cv;
    }

    const float bi = bias[0 * H + col];
    const float bf = bias[1 * H + col];
    const float bg = bias[2 * H + col];
    const float bo = bias[3 * H + col];
    const float wout = out_w[col];

    for (int s = 0; s < nsteps; ++s) {
        const float* xn = xnBase + (size_t)s * NN;
        for (int i = t; i < TR * 32; i += 512) {
            const int r = i >> 5, j2 = (i & 31) * 2;
            const float x = xn[row0 + r];
            const float e0 = fmaxf(0.f, fmaf(x, n_enc_w[j2],     n_enc_b[j2]));
            const float e1 = fmaxf(0.f, fmaf(x, n_enc_w[j2 + 1], n_enc_b[j2 + 1]));
            const int byte = r * ROWB + ((j2 * 2) ^ ((r & 7) << 4));
            *(unsigned int*)(Xls + byte) = pk2(e0, e1);
        }
        const f16* emb = embAll + (size_t)s * NN * 64;
        for (int i = t; i < TR * 16; i += 512) {
            const int r = i >> 4, j4 = (i & 15) * 4;
            const uint2 v = *(const uint2*)&emb[(size_t)(row0 + r) * 64 + j4];
            const int byte = r * ROWB + ((2 * (64 + j4)) ^ ((r & 7) << 4));
            *(uint2*)(Xls + byte) = v;
        }
        __syncthreads();

        const bool lastStep = (s == nsteps - 1);
        #pragma unroll 1
        for (int rt = 0; rt < RTN; ++rt) {
            const int arow = rt * 16 + lane15;
            const char* abase = Xls + arow * ROWB;
            f16x8 afrag[KSTEPS];
            #pragma unroll
            for (int ks = 0; ks < KSTEPS; ++ks) {
                const int byte = (ks * 64 + kgrp * 16) ^ ((arow & 7) << 4);
                afrag[ks] = ld_frag16(abase + byte);
            }
            __syncthreads();
            f32x4 acc[4];
            #pragma unroll
            for (int q = 0; q < 4; ++q)
                #pragma unroll
                for (int r = 0; r < 4; ++r) acc[q][r] = 0.f;
            #pragma unroll
            for (int ks = 0; ks < KSTEPS; ++ks)
                #pragma unroll
                for (int q = 0; q < 4; ++q)
                    acc[q] = __builtin_amdgcn_mfma_f32_16x16x32_f16(
                        afrag[ks], bfrag[q][ks], acc[q], 0, 0, 0);
            #pragma unroll
            for (int reg = 0; reg < 4; ++reg) {
                const int rl = rt * 16 + kgrp * 4 + reg;
                const int grow = row0 + rl;
                const size_t off = (size_t)grow * H + col;
                const int scn = rl * H + (col ^ CSWZ(rl));
                const float ig = fsigmoid(acc[0][reg] + bi);
                const float fg = fsigmoid(acc[1][reg] + bf);
                const float gg = ftanh(acc[2][reg] + bg);
                const float og = fsigmoid(acc[3][reg] + bo);
                const float c2 = fmaf(fg, clsN[scn], ig * gg);
                const float h2 = og * ftanh(c2);
                clsN[scn] = c2;
                const f16 h16 = (f16)h2;
                const int hbyte = rl * ROWB + ((2 * (H + col)) ^ ((rl & 7) << 4));
                *(f16*)(Xls + hbyte) = h16;
                if (lastStep) hIO[off] = h16;
                float pv = h2 * wout;
                pv += __shfl_xor(pv, 1);
                pv += __shfl_xor(pv, 2);
                pv += __shfl_xor(pv, 4);
                pv += __shfl_xor(pv, 8);
                if (lane15 == 0) out_part[rl][wv] = pv;
            }
        }
        __syncthreads();
        if (t < TR) {
            float sum = out_part[t][0];
            #pragma unroll
            for (int w = 1; w < 8; ++w) sum += out_part[t][w];
            outp[(size_t)s * NN + row0 + t] = sum + out_b[0];
        }
    }

    for (int i = t; i < TR * (H / 4); i += 512) {
        const int r = i >> 5, j4 = (i & 31) * 4;
        *(float4*)&c[(size_t)(row0 + r) * H + j4] =
            *(const float4*)&clsN[r * H + (j4 ^ CSWZ(r))];
    }
}

// ---------------- CSR build (once; inc is step-invariant) ----------------
__global__ __launch_bounds__(256) void count_kernel(
    const int* __restrict__ inc, int* __restrict__ cnt)
{
    const int slot = blockIdx.x * 256 + threadIdx.x;
    atomicAdd(&cnt[inc[slot]], 1);
}

__global__ __launch_bounds__(1024) void scan_kernel(
    const int* __restrict__ cnt, int* __restrict__ ptr)
{
    __shared__ int sums[1024];
    const int t = threadIdx.x;
    const int base = t * 32;
    int local[32];
    int s = 0;
    #pragma unroll
    for (int i = 0; i < 32; ++i) { local[i] = s; s += cnt[base + i]; }
    sums[t] = s;
    __syncthreads();
    for (int off = 1; off < 1024; off <<= 1) {
        int v = 0;
        if (t >= off) v = sums[t - off];
        __syncthreads();
        sums[t] += v;
        __syncthreads();
    }
    const int excl = sums[t] - s;
    #pragma unroll
    for (int i = 0; i < 32; ++i) ptr[base + i] = excl + local[i];
    if (t == 1023) ptr[NN] = sums[1023];
}

__global__ __launch_bounds__(256) void fill_kernel(
    const int* __restrict__ inc, const int* __restrict__ ptr,
    int* __restrict__ cur, int* __restrict__ rowidx)
{
    const int slot = blockIdx.x * 256 + threadIdx.x;
    const int n = inc[slot];
    const int pos = atomicAdd(&cur[n], 1);
    rowidx[ptr[n] + pos] = slot >> 1;
}

__global__ __launch_bounds__(256) void sort_csr_kernel(
    const int* __restrict__ ptr, int* __restrict__ rowidx)
{
    const int n = blockIdx.x * 256 + threadIdx.x;
    if (n >= NN) return;
    const int beg = ptr[n], end = ptr[n + 1];
    for (int i = beg; i < end - 1; ++i) {
        int mi = i, mv = rowidx[i];
        for (int j = i + 1; j < end; ++j) {
            const int v = rowidx[j];
            if (v < mv) { mv = v; mi = j; }
        }
        if (mi != i) { rowidx[mi] = rowidx[i]; rowidx[i] = mv; }
    }
}

// ---------------- weight transpose+convert (once) ----------------
__global__ __launch_bounds__(256) void transpose_w_kernel(
    const float* __restrict__ Wih, const float* __restrict__ Whh,
    f16* __restrict__ dst, int Hk, int K, int fourH)
{
    const int tid = blockIdx.x * 256 + threadIdx.x;
    if (tid >= K * fourH) return;
    const int col = tid / K, k = tid % K;
    const float v = (k < Hk) ? Wih[(size_t)k * fourH + col]
                             : Whh[(size_t)(k - Hk) * fourH + col];
    dst[tid] = (f16)v;
}

__global__ __launch_bounds__(256) void transpose_ee2_kernel(
    const float* __restrict__ ee_w, f16* __restrict__ dst)
{
    const int tid = blockIdx.x * 256 + threadIdx.x;
    if (tid >= 64 * 192) return;
    const int col = tid / 192, k = tid % 192;
    const int srcrow = (k < 128) ? k : (k - 64);
    dst[tid] = (f16)ee_w[(size_t)srcrow * 64 + col];
}

__global__ __launch_bounds__(256) void cvt_kernel(
    const float* __restrict__ src, f16* __restrict__ dst, int n2)
{
    const int i = blockIdx.x * 256 + threadIdx.x;
    if (i >= n2) return;
    const float2 v = ((const float2*)src)[i];
    ((unsigned int*)dst)[i] = pk2(v.x, v.y);
}

extern "C" void kernel_launch(void* const* d_in, const int* in_sizes, int n_in,
                              void* d_out, int out_size, void* d_ws, size_t ws_size,
                              hipStream_t stream) {
    const float* data_nodes = (const float*)d_in[0];
    const float* data_tE    = (const float*)d_in[1];
    const float* data_sE    = (const float*)d_in[2];
    const float* h_n0 = (const float*)d_in[3];
    const float* c_n0 = (const float*)d_in[4];
    const float* h_t0 = (const float*)d_in[5];
    const float* c_t0 = (const float*)d_in[6];
    const float* h_s0 = (const float*)d_in[7];
    const float* c_s0 = (const float*)d_in[8];
    const int*   inc  = (const int*)d_in[9];
    const float* t_enc_w = (const float*)d_in[10];
    const float* t_enc_b = (const float*)d_in[11];
    const float* t_Wih   = (const float*)d_in[12];
    const float* t_Whh   = (const float*)d_in[13];
    const float* t_b     = (const float*)d_in[14];
    const float* s_enc_w = (const float*)d_in[15];
    const float* s_enc_b = (const float*)d_in[16];
    const float* s_Wih   = (const float*)d_in[17];
    const float* s_Whh   = (const float*)d_in[18];
    const float* s_b     = (const float*)d_in[19];
    const float* n_enc_w = (const float*)d_in[20];
    const float* n_enc_b = (const float*)d_in[21];
    const float* ee_w    = (const float*)d_in[22];
    const float* ee_b    = (const float*)d_in[23];
    const float* n_Wih   = (const float*)d_in[24];
    const float* n_Whh   = (const float*)d_in[25];
    const float* n_b     = (const float*)d_in[26];
    const float* out_w   = (const float*)d_in[27];
    const float* out_b   = (const float*)d_in[28];
    float* out = (float*)d_out;

    // ---- chunk-size selection ----
    const size_t slotT = (size_t)NN * 64 * 2;
    const size_t slotS = (size_t)EE * 64 * 2;
    const size_t fixedB =
        (size_t)NN * 64 * 2 +           // htCarry
        (size_t)NN * 128 * 2 +          // hn16
        (size_t)NN * 128 * 4 +          // cn
        (size_t)NN * 64 * 4 +           // ct
        (size_t)EE * 64 * 4 +           // cs
        ((size_t)256 * 128 + 256 * 128 + 512 * 256 + 64 * 192) * 2 +
        ((size_t)(NN + 8) + 2 * (size_t)EE + NN + NN) * 4 +
        65536;
    int CH = 16;
    while (CH > 1 && fixedB + (size_t)CH * (slotT + slotS) > ws_size) CH >>= 1;

    // ---- workspace layout ----
    char* p = (char*)d_ws;
    f16*  htAll   = (f16*)p;  p += (size_t)CH * slotT;
    f16*  hsAll   = (f16*)p;  p += (size_t)CH * slotS;
    f16*  htCarry = (f16*)p;  p += (size_t)NN * 64 * 2;
    f16*  hn16    = (f16*)p;  p += (size_t)NN * 128 * 2;
    float* cn     = (float*)p; p += (size_t)NN * 128 * 4;
    float* ct     = (float*)p; p += (size_t)NN * 64 * 4;
    float* cs     = (float*)p; p += (size_t)EE * 64 * 4;
    f16*  Wt_t    = (f16*)p;  p += (size_t)256 * 128 * 2;
    f16*  Wt_s    = (f16*)p;  p += (size_t)256 * 128 * 2;
    f16*  Wt_n    = (f16*)p;  p += (size_t)512 * 256 * 2;
    f16*  Wt_ee2  = (f16*)p;  p += (size_t)64 * 192 * 2;
    int*  csr_ptr = (int*)p;  p += (size_t)(NN + 8) * 4;
    int*  csr_row = (int*)p;  p += (size_t)2 * EE * 4;
    int*  cnt     = (int*)p;  p += (size_t)NN * 4;
    int*  cur     = (int*)p;  p += (size_t)NN * 4;

    // ---- one-time: state init, weight conversion, CSR ----
    cvt_kernel<<<(NN * 64 / 2 + 255) / 256, 256, 0, stream>>>(h_t0, htCarry, NN * 64 / 2);
    cvt_kernel<<<(EE * 64 / 2 + 255) / 256, 256, 0, stream>>>(
        h_s0, hsAll + (size_t)(CH - 1) * EE * 64, EE * 64 / 2);
    cvt_kernel<<<(NN * 128 / 2 + 255) / 256, 256, 0, stream>>>(h_n0, hn16, NN * 128 / 2);
    hipMemcpyAsync(cn, c_n0, (size_t)NN * 128 * 4, hipMemcpyDeviceToDevice, stream);

    transpose_w_kernel<<<(256 * 128 + 255) / 256, 256, 0, stream>>>(t_Wih, t_Whh, Wt_t, 64, 128, 256);
    transpose_w_kernel<<<(256 * 128 + 255) / 256, 256, 0, stream>>>(s_Wih, s_Whh, Wt_s, 64, 128, 256);
    transpose_w_kernel<<<(512 * 256 + 255) / 256, 256, 0, stream>>>(n_Wih, n_Whh, Wt_n, 128, 256, 512);
    transpose_ee2_kernel<<<(64 * 192 + 255) / 256, 256, 0, stream>>>(ee_w, Wt_ee2);

    hipMemsetAsync(cnt, 0, NN * sizeof(int), stream);
    hipMemsetAsync(cur, 0, NN * sizeof(int), stream);
    count_kernel<<<(2 * EE) / 256, 256, 0, stream>>>(inc, cnt);
    scan_kernel<<<1, 1024, 0, stream>>>(cnt, csr_ptr);
    fill_kernel<<<(2 * EE) / 256, 256, 0, stream>>>(inc, csr_ptr, cur, csr_row);
    sort_csr_kernel<<<NN / 256, 256, 0, stream>>>(csr_ptr, csr_row);

    const int edgeGrid = NN / 64 + EE / 64;   // 2560

    for (int c0 = 0; c0 < S_LEN; c0 += CH) {
        edge_mega<<<edgeGrid, 256, 0, stream>>>(
            data_tE + (size_t)c0 * NN * 2, data_sE + (size_t)c0 * EE * 2,
            t_enc_w, t_enc_b, s_enc_w, s_enc_b,
            Wt_t, Wt_s, t_b, s_b,
            htAll, hsAll, htCarry,
            (c0 == 0) ? c_t0 : ct, (c0 == 0) ? c_s0 : cs, ct, cs,
            CH, (c0 + CH < S_LEN) ? 1 : 0);

        gather_embed_mega<<<CH * (NN / 64), 256, 0, stream>>>(
            htAll, hsAll, csr_ptr, csr_row, Wt_ee2, ee_b);

        node_mega<<<NN / 128, 512, 0, stream>>>(
            data_nodes + (size_t)c0 * NN, htAll, Wt_n, n_b,
            n_enc_w, n_enc_b, out_w, out_b, hn16, cn,
            out + (size_t)c0 * NN, CH);
    }
}

// Round 19
// 933.707 us; speedup vs baseline: 1.0349x; 1.0349x over previous
//
#include <hip/hip_runtime.h>
#include <math.h>

// SRNN: S=16 steps, N=32768 nodes, E=131072 spatial edges.
// f16 MFMA gate GEMMs, B-resident weights. Numerics (14/14 stable):
//  - edge/node per-thread arithmetic = verified forms (absmax 3.90625e-3)
//  - CSR sorted ascending; agg as hi/lo f16 pair (K=192, MFMA order ks 0..5)
// REVERT to the r17-measured 932us configuration: edge_mega with uint2
// h-flush (r18's 4-B flush cost +16 insts/thread-step in an issue-bound
// kernel, conflicts unchanged -> reverted). Batched gather (emb in-place
// into htAll) + node_mega (c in LDS, enc on-the-fly) unchanged.

#define S_LEN 16
#define NN 32768
#define EE 131072

typedef _Float16 f16;
typedef _Float16 f16x8 __attribute__((ext_vector_type(8)));
typedef float f32x4 __attribute__((ext_vector_type(4)));

__device__ __forceinline__ float fsigmoid(float x) {
    return __builtin_amdgcn_rcpf(1.0f + __builtin_amdgcn_exp2f(-1.44269504f * x));
}
__device__ __forceinline__ float ftanh(float x) {
    const float e = __builtin_amdgcn_exp2f(2.88539008f * x);
    return 1.0f - 2.0f * __builtin_amdgcn_rcpf(e + 1.0f);
}

__device__ __forceinline__ unsigned int pk2(float a, float b) {
    union { f16 h[2]; unsigned int u; } x;
    x.h[0] = (f16)a; x.h[1] = (f16)b;
    return x.u;
}

__device__ __forceinline__ f16x8 ld_frag16(const void* p) {
    union { uint4 v; f16x8 f; } x;
    x.v = *(const uint4*)p;
    return x.f;
}

#define CSWZ(rl) (((((rl) >> 2) & 3) ^ ((rl) & 3)) << 4)

// ---------------- multi-step edge LSTM (temporal + spatial), H=64, TR=64 ----
__global__ __launch_bounds__(256) void edge_mega(
    const float* __restrict__ xT, const float* __restrict__ xS,
    const float* __restrict__ t_enc_w, const float* __restrict__ t_enc_b,
    const float* __restrict__ s_enc_w, const float* __restrict__ s_enc_b,
    const f16* __restrict__ WtT, const f16* __restrict__ WtS,
    const float* __restrict__ biasT, const float* __restrict__ biasS,
    f16* __restrict__ htAll, f16* __restrict__ hsAll,
    f16* __restrict__ htCarry,
    const float* __restrict__ cInT, const float* __restrict__ cInS,
    float* __restrict__ cOutT, float* __restrict__ cOutS,
    const int nsteps, const int writeC)
{
    constexpr int H = 64, K = 128, KSTEPS = 4, ROWB = 256, TR = 64;
    constexpr int RTN = TR / 16;
    __shared__ __align__(16) char Xls[TR * ROWB];
    __shared__ __align__(16) float cls[TR * H];
    __shared__ __align__(16) f16 hnx[TR * H];

    const int bT = NN / TR;
    const bool isT = (int)blockIdx.x < bT;
    const int row0 = (isT ? blockIdx.x : blockIdx.x - bT) * TR;
    const float* xbase = isT ? xT : xS;
    const size_t xstep = (size_t)(isT ? NN : EE) * 2;
    const float* enc_w = isT ? t_enc_w : s_enc_w;
    const float* enc_b = isT ? t_enc_b : s_enc_b;
    const f16*   Wt    = isT ? WtT : WtS;
    const float* bias  = isT ? biasT : biasS;
    f16* hAll = isT ? htAll : hsAll;
    const size_t hstep = (size_t)(isT ? NN : EE) * 64;
    const float* cIn  = (isT ? cInT : cInS) + (size_t)row0 * H;
    float*       cOut = (isT ? cOutT : cOutS) + (size_t)row0 * H;

    const int t = threadIdx.x;
    const int wv = t >> 6, l = t & 63;
    const int lane15 = l & 15, kgrp = l >> 4;
    const int col = wv * 16 + lane15;

    f16x8 bfrag[4][KSTEPS];
    #pragma unroll
    for (int q = 0; q < 4; ++q) {
        const int colq = q * H + col;
        const f16* bp = Wt + (size_t)colq * K + kgrp * 8;
        #pragma unroll
        for (int ks = 0; ks < KSTEPS; ++ks)
            bfrag[q][ks] = ld_frag16(bp + ks * 32);
    }

    for (int i = t; i < TR * H; i += 256) {
        const int r = i >> 6, j = i & 63;
        cls[(r << 6) + (j ^ CSWZ(r))] = cIn[i];
    }
    {
        const f16* hInit = isT ? (htCarry + (size_t)row0 * H)
                               : (hAll + (size_t)(nsteps - 1) * hstep + (size_t)row0 * H);
        for (int i = t; i < TR * (H / 4); i += 256) {
            const int r = i / (H / 4), j4 = (i % (H / 4)) * 4;
            const uint2 v = *(const uint2*)&hInit[(size_t)r * H + j4];
            const int byte = r * ROWB + ((H * 2 + j4 * 2) ^ ((r & 7) << 4));
            *(uint2*)(Xls + byte) = v;
        }
    }

    const float bi = bias[0 * H + col];
    const float bf = bias[1 * H + col];
    const float bg = bias[2 * H + col];
    const float bo = bias[3 * H + col];

    float xr0[8], xr1[8];
    {
        const float* xf = xbase;
        #pragma unroll
        for (int k2 = 0; k2 < 8; ++k2) {
            const int r = (t + k2 * 256) >> 5;
            xr0[k2] = xf[(size_t)(row0 + r) * 2 + 0];
            xr1[k2] = xf[(size_t)(row0 + r) * 2 + 1];
        }
    }

    for (int s = 0; s < nsteps; ++s) {
        #pragma unroll
        for (int k2 = 0; k2 < 8; ++k2) {
            const int i = t + k2 * 256;
            const int r = i >> 5, j2 = (i & 31) * 2;
            const float x0 = xr0[k2];
            const float x1 = xr1[k2];
            const float e0 = fmaxf(0.f, fmaf(x0, enc_w[j2],     fmaf(x1, enc_w[H + j2],     enc_b[j2])));
            const float e1 = fmaxf(0.f, fmaf(x0, enc_w[j2 + 1], fmaf(x1, enc_w[H + j2 + 1], enc_b[j2 + 1])));
            const int byte = r * ROWB + ((j2 * 2) ^ ((r & 7) << 4));
            *(unsigned int*)(Xls + byte) = pk2(e0, e1);
        }
        __syncthreads();

        if (s + 1 < nsteps) {
            const float* xf = xbase + (size_t)(s + 1) * xstep;
            #pragma unroll
            for (int k2 = 0; k2 < 8; ++k2) {
                const int r = (t + k2 * 256) >> 5;
                xr0[k2] = xf[(size_t)(row0 + r) * 2 + 0];
                xr1[k2] = xf[(size_t)(row0 + r) * 2 + 1];
            }
        }

        #pragma unroll
        for (int rt = 0; rt < RTN; ++rt) {
            const int arow = rt * 16 + lane15;
            const char* abase = Xls + arow * ROWB;
            f16x8 afrag[KSTEPS];
            #pragma unroll
            for (int ks = 0; ks < KSTEPS; ++ks) {
                const int byte = (ks * 64 + kgrp * 16) ^ ((arow & 7) << 4);
                afrag[ks] = ld_frag16(abase + byte);
            }
            f32x4 acc[4];
            #pragma unroll
            for (int q = 0; q < 4; ++q)
                #pragma unroll
                for (int r = 0; r < 4; ++r) acc[q][r] = 0.f;
            #pragma unroll
            for (int ks = 0; ks < KSTEPS; ++ks)
                #pragma unroll
                for (int q = 0; q < 4; ++q)
                    acc[q] = __builtin_amdgcn_mfma_f32_16x16x32_f16(
                        afrag[ks], bfrag[q][ks], acc[q], 0, 0, 0);
            #pragma unroll
            for (int reg = 0; reg < 4; ++reg) {
                const int rl = rt * 16 + kgrp * 4 + reg;
                const int sc = (rl << 6) + (col ^ CSWZ(rl));
                const float ig = fsigmoid(acc[0][reg] + bi);
                const float fg = fsigmoid(acc[1][reg] + bf);
                const float gg = ftanh(acc[2][reg] + bg);
                const float og = fsigmoid(acc[3][reg] + bo);
                const float c2 = fmaf(fg, cls[sc], ig * gg);
                cls[sc] = c2;
                hnx[sc] = (f16)(og * ftanh(c2));
            }
        }
        __syncthreads();

        // flush h: hnx (swizzled) -> global slot s (coalesced) AND panel h-half
        f16* hOut = hAll + (size_t)s * hstep + (size_t)row0 * H;
        const bool carry = isT && (s == nsteps - 1);
        for (int i = t; i < TR * (H / 4); i += 256) {
            const int r = i / (H / 4), j4 = (i % (H / 4)) * 4;
            const uint2 v = *(const uint2*)&hnx[(r << 6) + (j4 ^ CSWZ(r))];
            *(uint2*)&hOut[(size_t)r * H + j4] = v;
            if (carry) *(uint2*)&htCarry[(size_t)(row0 + r) * H + j4] = v;
            const int byte = r * ROWB + ((H * 2 + j4 * 2) ^ ((r & 7) << 4));
            *(uint2*)(Xls + byte) = v;
        }
    }

    if (writeC) {
        for (int i = t; i < TR * H; i += 256) {
            const int r = i >> 6, j = i & 63;
            cOut[i] = cls[(r << 6) + (j ^ CSWZ(r))];
        }
    }
}

// ---------------- batched gather + embed (all chunk steps, one dispatch) ----
__global__ __launch_bounds__(256) void gather_embed_mega(
    const f16* __restrict__ htAll, const f16* __restrict__ hsAll,
    const int* __restrict__ ptr, const int* __restrict__ rowidx,
    const f16* __restrict__ Wt_ee2,  // [64][192]
    const float* __restrict__ ee_b)
{
    constexpr int TR = 64, K = 192, KSTEPS = 6, ROWB = 256;
    __shared__ __align__(16) char Xls[TR * ROWB];
    const int k2    = blockIdx.x >> 9;
    const int panel = blockIdx.x & 511;
    const int row0 = panel * TR;
    f16* htSlot = (f16*)htAll + (size_t)k2 * NN * 64;
    const f16* hsSlot = hsAll + (size_t)k2 * EE * 64;

    const int t = threadIdx.x;
    const int wv = t >> 6, l = t & 63;
    const int lane15 = l & 15, kgrp = l >> 4;
    const int col = wv * 16 + lane15;

    f16x8 bfrag[KSTEPS];
    {
        const f16* bp = Wt_ee2 + (size_t)col * K + kgrp * 8;
        #pragma unroll
        for (int ks = 0; ks < KSTEPS; ++ks) bfrag[ks] = ld_frag16(bp + ks * 32);
    }

    f16x8 af0[4], af1[4];
    #pragma unroll
    for (int rt = 0; rt < 4; ++rt) {
        const int arow = rt * 16 + lane15;
        af0[rt] = ld_frag16(&htSlot[(size_t)(row0 + arow) * 64 + kgrp * 8]);
        af1[rt] = ld_frag16(&htSlot[(size_t)(row0 + arow) * 64 + 32 + kgrp * 8]);
    }

    {
        const int r = t >> 2, q = t & 3;
        const int n = row0 + r;
        const int beg = ptr[n], end = ptr[n + 1];
        const unsigned int* hs32 = (const unsigned int*)hsSlot;
        float acc[16];
        #pragma unroll
        for (int j = 0; j < 16; ++j) acc[j] = 0.f;
        for (int i = beg; i < end; ++i) {
            const int e = rowidx[i];
            const unsigned int* ep = hs32 + (size_t)e * 32 + q * 8;
            #pragma unroll
            for (int j = 0; j < 8; ++j) {
                union { unsigned int u; f16 h[2]; } v;
                v.u = ep[j];
                acc[2 * j]     += (float)v.h[0];
                acc[2 * j + 1] += (float)v.h[1];
            }
        }
        #pragma unroll
        for (int j = 0; j < 8; ++j) {
            const float a0 = acc[2 * j], a1 = acc[2 * j + 1];
            const f16 h0 = (f16)a0, h1 = (f16)a1;
            const f16 l0 = (f16)(a0 - (float)h0), l1 = (f16)(a1 - (float)h1);
            union { f16 h[2]; unsigned int u; } hi, lo;
            hi.h[0] = h0; hi.h[1] = h1;
            lo.h[0] = l0; lo.h[1] = l1;
            const int bhi = r * ROWB + ((q * 32 + j * 4) ^ ((r & 7) << 4));
            const int blo = r * ROWB + ((128 + q * 32 + j * 4) ^ ((r & 7) << 4));
            *(unsigned int*)(Xls + bhi) = hi.u;
            *(unsigned int*)(Xls + blo) = lo.u;
        }
    }
    __syncthreads();

    const float bb = ee_b[col];
    #pragma unroll
    for (int rt = 0; rt < TR / 16; ++rt) {
        const int arow = rt * 16 + lane15;
        const char* abase = Xls + arow * ROWB;
        f16x8 afrag[KSTEPS];
        afrag[0] = af0[rt];
        afrag[1] = af1[rt];
        #pragma unroll
        for (int ks = 2; ks < KSTEPS; ++ks) {
            const int byte = (((ks - 2) * 64) + kgrp * 16) ^ ((arow & 7) << 4);
            afrag[ks] = ld_frag16(abase + byte);
        }
        f32x4 acc;
        #pragma unroll
        for (int r = 0; r < 4; ++r) acc[r] = 0.f;
        #pragma unroll
        for (int ks = 0; ks < KSTEPS; ++ks)
            acc = __builtin_amdgcn_mfma_f32_16x16x32_f16(afrag[ks], bfrag[ks], acc, 0, 0, 0);
        #pragma unroll
        for (int reg = 0; reg < 4; ++reg) {
            const int grow = row0 + rt * 16 + kgrp * 4 + reg;
            htSlot[(size_t)grow * 64 + col] = (f16)fmaxf(0.f, acc[reg] + bb);
        }
    }
}

// ---------------- multi-step node LSTM + fused output projection ------------
__global__ __launch_bounds__(512) void node_mega(
    const float* __restrict__ xnBase,
    const f16* __restrict__ embAll,
    const f16* __restrict__ Wt,
    const float* __restrict__ bias,
    const float* __restrict__ n_enc_w, const float* __restrict__ n_enc_b,
    const float* __restrict__ out_w, const float* __restrict__ out_b,
    f16* __restrict__ hIO,
    float* __restrict__ c,
    float* __restrict__ outp,
    const int nsteps)
{
    constexpr int H = 128, K = 256, KSTEPS = 8, ROWB = 512, TR = 128;
    constexpr int RTN = TR / 16;
    __shared__ __align__(16) char Xls[TR * ROWB];
    __shared__ __align__(16) float clsN[TR * H];
    __shared__ float out_part[TR][8];

    const int row0 = blockIdx.x * TR;
    const int t = threadIdx.x;
    const int wv = t >> 6, l = t & 63;
    const int lane15 = l & 15, kgrp = l >> 4;
    const int col = wv * 16 + lane15;

    f16x8 bfrag[4][KSTEPS];
    #pragma unroll
    for (int q = 0; q < 4; ++q) {
        const int colq = q * H + col;
        const f16* bp = Wt + (size_t)colq * K + kgrp * 8;
        #pragma unroll
        for (int ks = 0; ks < KSTEPS; ++ks)
            bfrag[q][ks] = ld_frag16(bp + ks * 32);
    }

    for (int i = t; i < TR * (H / 4); i += 512) {
        const int r = i >> 5, j4 = (i & 31) * 4;
        const uint2 v = *(const uint2*)&hIO[(size_t)(row0 + r) * H + j4];
        const int byte = r * ROWB + ((H * 2 + j4 * 2) ^ ((r & 7) << 4));
        *(uint2*)(Xls + byte) = v;
        const float4 cv = *(const float4*)&c[(size_t)(row0 + r) * H + j4];
        *(float4*)&clsN[r * H + (j4 ^ CSWZ(r))] = cv;
    }

    const float bi = bias[0 * H + col];
    const float bf = bias[1 * H + col];
    const float bg = bias[2 * H + col];
    const float bo = bias[3 * H + col];
    const float wout = out_w[col];

    for (int s = 0; s < nsteps; ++s) {
        const float* xn = xnBase + (size_t)s * NN;
        for (int i = t; i < TR * 32; i += 512) {
            const int r = i >> 5, j2 = (i & 31) * 2;
            const float x = xn[row0 + r];
            const float e0 = fmaxf(0.f, fmaf(x, n_enc_w[j2],     n_enc_b[j2]));
            const float e1 = fmaxf(0.f, fmaf(x, n_enc_w[j2 + 1], n_enc_b[j2 + 1]));
            const int byte = r * ROWB + ((j2 * 2) ^ ((r & 7) << 4));
            *(unsigned int*)(Xls + byte) = pk2(e0, e1);
        }
        const f16* emb = embAll + (size_t)s * NN * 64;
        for (int i = t; i < TR * 16; i += 512) {
            const int r = i >> 4, j4 = (i & 15) * 4;
            const uint2 v = *(const uint2*)&emb[(size_t)(row0 + r) * 64 + j4];
            const int byte = r * ROWB + ((2 * (64 + j4)) ^ ((r & 7) << 4));
            *(uint2*)(Xls + byte) = v;
        }
        __syncthreads();

        const bool lastStep = (s == nsteps - 1);
        #pragma unroll 1
        for (int rt = 0; rt < RTN; ++rt) {
            const int arow = rt * 16 + lane15;
            const char* abase = Xls + arow * ROWB;
            f16x8 afrag[KSTEPS];
            #pragma unroll
            for (int ks = 0; ks < KSTEPS; ++ks) {
                const int byte = (ks * 64 + kgrp * 16) ^ ((arow & 7) << 4);
                afrag[ks] = ld_frag16(abase + byte);
            }
            __syncthreads();
            f32x4 acc[4];
            #pragma unroll
            for (int q = 0; q < 4; ++q)
                #pragma unroll
                for (int r = 0; r < 4; ++r) acc[q][r] = 0.f;
            #pragma unroll
            for (int ks = 0; ks < KSTEPS; ++ks)
                #pragma unroll
                for (int q = 0; q < 4; ++q)
                    acc[q] = __builtin_amdgcn_mfma_f32_16x16x32_f16(
                        afrag[ks], bfrag[q][ks], acc[q], 0, 0, 0);
            #pragma unroll
            for (int reg = 0; reg < 4; ++reg) {
                const int rl = rt * 16 + kgrp * 4 + reg;
                const int grow = row0 + rl;
                const size_t off = (size_t)grow * H + col;
                const int scn = rl * H + (col ^ CSWZ(rl));
                const float ig = fsigmoid(acc[0][reg] + bi);
                const float fg = fsigmoid(acc[1][reg] + bf);
                const float gg = ftanh(acc[2][reg] + bg);
                const float og = fsigmoid(acc[3][reg] + bo);
                const float c2 = fmaf(fg, clsN[scn], ig * gg);
                const float h2 = og * ftanh(c2);
                clsN[scn] = c2;
                const f16 h16 = (f16)h2;
                const int hbyte = rl * ROWB + ((2 * (H + col)) ^ ((rl & 7) << 4));
                *(f16*)(Xls + hbyte) = h16;
                if (lastStep) hIO[off] = h16;
                float pv = h2 * wout;
                pv += __shfl_xor(pv, 1);
                pv += __shfl_xor(pv, 2);
                pv += __shfl_xor(pv, 4);
                pv += __shfl_xor(pv, 8);
                if (lane15 == 0) out_part[rl][wv] = pv;
            }
        }
        __syncthreads();
        if (t < TR) {
            float sum = out_part[t][0];
            #pragma unroll
            for (int w = 1; w < 8; ++w) sum += out_part[t][w];
            outp[(size_t)s * NN + row0 + t] = sum + out_b[0];
        }
    }

    for (int i = t; i < TR * (H / 4); i += 512) {
        const int r = i >> 5, j4 = (i & 31) * 4;
        *(float4*)&c[(size_t)(row0 + r) * H + j4] =
            *(const float4*)&clsN[r * H + (j4 ^ CSWZ(r))];
    }
}

// ---------------- CSR build (once; inc is step-invariant) ----------------
__global__ __launch_bounds__(256) void count_kernel(
    const int* __restrict__ inc, int* __restrict__ cnt)
{
    const int slot = blockIdx.x * 256 + threadIdx.x;
    atomicAdd(&cnt[inc[slot]], 1);
}

__global__ __launch_bounds__(1024) void scan_kernel(
    const int* __restrict__ cnt, int* __restrict__ ptr)
{
    __shared__ int sums[1024];
    const int t = threadIdx.x;
    const int base = t * 32;
    int local[32];
    int s = 0;
    #pragma unroll
    for (int i = 0; i < 32; ++i) { local[i] = s; s += cnt[base + i]; }
    sums[t] = s;
    __syncthreads();
    for (int off = 1; off < 1024; off <<= 1) {
        int v = 0;
        if (t >= off) v = sums[t - off];
        __syncthreads();
        sums[t] += v;
        __syncthreads();
    }
    const int excl = sums[t] - s;
    #pragma unroll
    for (int i = 0; i < 32; ++i) ptr[base + i] = excl + local[i];
    if (t == 1023) ptr[NN] = sums[1023];
}

__global__ __launch_bounds__(256) void fill_kernel(
    const int* __restrict__ inc, const int* __restrict__ ptr,
    int* __restrict__ cur, int* __restrict__ rowidx)
{
    const int slot = blockIdx.x * 256 + threadIdx.x;
    const int n = inc[slot];
    const int pos = atomicAdd(&cur[n], 1);
    rowidx[ptr[n] + pos] = slot >> 1;
}

__global__ __launch_bounds__(256) void sort_csr_kernel(
    const int* __restrict__ ptr, int* __restrict__ rowidx)
{
    const int n = blockIdx.x * 256 + threadIdx.x;
    if (n >= NN) return;
    const int beg = ptr[n], end = ptr[n + 1];
    for (int i = beg; i < end - 1; ++i) {
        int mi = i, mv = rowidx[i];
        for (int j = i + 1; j < end; ++j) {
            const int v = rowidx[j];
            if (v < mv) { mv = v; mi = j; }
        }
        if (mi != i) { rowidx[mi] = rowidx[i]; rowidx[i] = mv; }
    }
}

// ---------------- weight transpose+convert (once) ----------------
__global__ __launch_bounds__(256) void transpose_w_kernel(
    const float* __restrict__ Wih, const float* __restrict__ Whh,
    f16* __restrict__ dst, int Hk, int K, int fourH)
{
    const int tid = blockIdx.x * 256 + threadIdx.x;
    if (tid >= K * fourH) return;
    const int col = tid / K, k = tid % K;
    const float v = (k < Hk) ? Wih[(size_t)k * fourH + col]
                             : Whh[(size_t)(k - Hk) * fourH + col];
    dst[tid] = (f16)v;
}

__global__ __launch_bounds__(256) void transpose_ee2_kernel(
    const float* __restrict__ ee_w, f16* __restrict__ dst)
{
    const int tid = blockIdx.x * 256 + threadIdx.x;
    if (tid >= 64 * 192) return;
    const int col = tid / 192, k = tid % 192;
    const int srcrow = (k < 128) ? k : (k - 64);
    dst[tid] = (f16)ee_w[(size_t)srcrow * 64 + col];
}

__global__ __launch_bounds__(256) void cvt_kernel(
    const float* __restrict__ src, f16* __restrict__ dst, int n2)
{
    const int i = blockIdx.x * 256 + threadIdx.x;
    if (i >= n2) return;
    const float2 v = ((const float2*)src)[i];
    ((unsigned int*)dst)[i] = pk2(v.x, v.y);
}

extern "C" void kernel_launch(void* const* d_in, const int* in_sizes, int n_in,
                              void* d_out, int out_size, void* d_ws, size_t ws_size,
                              hipStream_t stream) {
    const float* data_nodes = (const float*)d_in[0];
    const float* data_tE    = (const float*)d_in[1];
    const float* data_sE    = (const float*)d_in[2];
    const float* h_n0 = (const float*)d_in[3];
    const float* c_n0 = (const float*)d_in[4];
    const float* h_t0 = (const float*)d_in[5];
    const float* c_t0 = (const float*)d_in[6];
    const float* h_s0 = (const float*)d_in[7];
    const float* c_s0 = (const float*)d_in[8];
    const int*   inc  = (const int*)d_in[9];
    const float* t_enc_w = (const float*)d_in[10];
    const float* t_enc_b = (const float*)d_in[11];
    const float* t_Wih   = (const float*)d_in[12];
    const float* t_Whh   = (const float*)d_in[13];
    const float* t_b     = (const float*)d_in[14];
    const float* s_enc_w = (const float*)d_in[15];
    const float* s_enc_b = (const float*)d_in[16];
    const float* s_Wih   = (const float*)d_in[17];
    const float* s_Whh   = (const float*)d_in[18];
    const float* s_b     = (const float*)d_in[19];
    const float* n_enc_w = (const float*)d_in[20];
    const float* n_enc_b = (const float*)d_in[21];
    const float* ee_w    = (const float*)d_in[22];
    const float* ee_b    = (const float*)d_in[23];
    const float* n_Wih   = (const float*)d_in[24];
    const float* n_Whh   = (const float*)d_in[25];
    const float* n_b     = (const float*)d_in[26];
    const float* out_w   = (const float*)d_in[27];
    const float* out_b   = (const float*)d_in[28];
    float* out = (float*)d_out;

    // ---- chunk-size selection ----
    const size_t slotT = (size_t)NN * 64 * 2;
    const size_t slotS = (size_t)EE * 64 * 2;
    const size_t fixedB =
        (size_t)NN * 64 * 2 +           // htCarry
        (size_t)NN * 128 * 2 +          // hn16
        (size_t)NN * 128 * 4 +          // cn
        (size_t)NN * 64 * 4 +           // ct
        (size_t)EE * 64 * 4 +           // cs
        ((size_t)256 * 128 + 256 * 128 + 512 * 256 + 64 * 192) * 2 +
        ((size_t)(NN + 8) + 2 * (size_t)EE + NN + NN) * 4 +
        65536;
    int CH = 16;
    while (CH > 1 && fixedB + (size_t)CH * (slotT + slotS) > ws_size) CH >>= 1;

    // ---- workspace layout ----
    char* p = (char*)d_ws;
    f16*  htAll   = (f16*)p;  p += (size_t)CH * slotT;
    f16*  hsAll   = (f16*)p;  p += (size_t)CH * slotS;
    f16*  htCarry = (f16*)p;  p += (size_t)NN * 64 * 2;
    f16*  hn16    = (f16*)p;  p += (size_t)NN * 128 * 2;
    float* cn     = (float*)p; p += (size_t)NN * 128 * 4;
    float* ct     = (float*)p; p += (size_t)NN * 64 * 4;
    float* cs     = (float*)p; p += (size_t)EE * 64 * 4;
    f16*  Wt_t    = (f16*)p;  p += (size_t)256 * 128 * 2;
    f16*  Wt_s    = (f16*)p;  p += (size_t)256 * 128 * 2;
    f16*  Wt_n    = (f16*)p;  p += (size_t)512 * 256 * 2;
    f16*  Wt_ee2  = (f16*)p;  p += (size_t)64 * 192 * 2;
    int*  csr_ptr = (int*)p;  p += (size_t)(NN + 8) * 4;
    int*  csr_row = (int*)p;  p += (size_t)2 * EE * 4;
    int*  cnt     = (int*)p;  p += (size_t)NN * 4;
    int*  cur     = (int*)p;  p += (size_t)NN * 4;

    // ---- one-time: state init, weight conversion, CSR ----
    cvt_kernel<<<(NN * 64 / 2 + 255) / 256, 256, 0, stream>>>(h_t0, htCarry, NN * 64 / 2);
    cvt_kernel<<<(EE * 64 / 2 + 255) / 256, 256, 0, stream>>>(
        h_s0, hsAll + (size_t)(CH - 1) * EE * 64, EE * 64 / 2);
    cvt_kernel<<<(NN * 128 / 2 + 255) / 256, 256, 0, stream>>>(h_n0, hn16, NN * 128 / 2);
    hipMemcpyAsync(cn, c_n0, (size_t)NN * 128 * 4, hipMemcpyDeviceToDevice, stream);

    transpose_w_kernel<<<(256 * 128 + 255) / 256, 256, 0, stream>>>(t_Wih, t_Whh, Wt_t, 64, 128, 256);
    transpose_w_kernel<<<(256 * 128 + 255) / 256, 256, 0, stream>>>(s_Wih, s_Whh, Wt_s, 64, 128, 256);
    transpose_w_kernel<<<(512 * 256 + 255) / 256, 256, 0, stream>>>(n_Wih, n_Whh, Wt_n, 128, 256, 512);
    transpose_ee2_kernel<<<(64 * 192 + 255) / 256, 256, 0, stream>>>(ee_w, Wt_ee2);

    hipMemsetAsync(cnt, 0, NN * sizeof(int), stream);
    hipMemsetAsync(cur, 0, NN * sizeof(int), stream);
    count_kernel<<<(2 * EE) / 256, 256, 0, stream>>>(inc, cnt);
    scan_kernel<<<1, 1024, 0, stream>>>(cnt, csr_ptr);
    fill_kernel<<<(2 * EE) / 256, 256, 0, stream>>>(inc, csr_ptr, cur, csr_row);
    sort_csr_kernel<<<NN / 256, 256, 0, stream>>>(csr_ptr, csr_row);

    const int edgeGrid = NN / 64 + EE / 64;   // 2560

    for (int c0 = 0; c0 < S_LEN; c0 += CH) {
        edge_mega<<<edgeGrid, 256, 0, stream>>>(
            data_tE + (size_t)c0 * NN * 2, data_sE + (size_t)c0 * EE * 2,
            t_enc_w, t_enc_b, s_enc_w, s_enc_b,
            Wt_t, Wt_s, t_b, s_b,
            htAll, hsAll, htCarry,
            (c0 == 0) ? c_t0 : ct, (c0 == 0) ? c_s0 : cs, ct, cs,
            CH, (c0 + CH < S_LEN) ? 1 : 0);

        gather_embed_mega<<<CH * (NN / 64), 256, 0, stream>>>(
            htAll, hsAll, csr_ptr, csr_row, Wt_ee2, ee_b);

        node_mega<<<NN / 128, 512, 0, stream>>>(
            data_nodes + (size_t)c0 * NN, htAll, Wt_n, n_b,
            n_enc_w, n_enc_b, out_w, out_b, hn16, cn,
            out + (size_t)c0 * NN, CH);
    }
}